// Round 1
// 798.129 us; speedup vs baseline: 1.0018x; 1.0018x over previous
//
#include <hip/hip_runtime.h>
#include <math.h>

typedef unsigned int u32;
typedef unsigned long long u64;

#define B_ 16
#define L_ 1024
#define H_ 8
#define E_ 64
#define C_ 512            // H_*E_
#define NB_SEL 8          // blocks per (scale,b) in k_sel
#define GCH 8             // channels per k_stats block
#define TC 32             // k_corr time-chunk
#define CAPR 160          // k_corr<S> circular K-buffer rows (= 127 + TC + 1)
#define CAP1 192          // k_corr1 ring rows: 127 hist + 32 cur + 32 async-stage

// scale indexing: sidx 0 -> s=1 (Ls=1024), 1 -> s=2 (512), 2 -> s=4 (256)
__device__ __forceinline__ size_t co(int sidx) {       // corr elem offset
  return sidx == 0 ? 0u : (sidx == 1 ? 8388608u : 12582912u);
}
__device__ __forceinline__ u32 pk_off(int sidx) {      // pk elem offset in o-region
  return sidx == 0 ? 0u : (sidx == 1 ? 3211264u : 4816896u);
}
__device__ __forceinline__ u32 pk_cap(int sidx) { return 200704u >> sidx; }

__device__ __forceinline__ u32 f2key(float f) {
  u32 u = __float_as_uint(f);
  return (u & 0x80000000u) ? ~u : (u | 0x80000000u);
}
__device__ __forceinline__ float key2f(u32 k) {
  u32 u = (k & 0x80000000u) ? (k ^ 0x80000000u) : ~k;
  return __uint_as_float(u);
}

// direct global->LDS DMA, 16B/lane; LDS dest = wave-uniform base + lane*16
using u32g = __attribute__((address_space(1))) const unsigned int;
using u32l = __attribute__((address_space(3))) unsigned int;
__device__ __forceinline__ void gload16(const float* g, float* l) {
  __builtin_amdgcn_global_load_lds((u32g*)g, (u32l*)l, 16, 0, 0);
}

// ---------------------------------------------------------------------------
// K_init: zero control state once (single-pass pipeline -> no mid-run resets)
// ---------------------------------------------------------------------------
__global__ void k_init(u32* histA, u32* histB, u32* peak_cnt, u32* done,
                       double* s1, double* s2, float* cm) {
  const int gid = blockIdx.x * 256 + threadIdx.x;
  const int gs = gridDim.x * 256;
  for (int i = gid; i < 3 * 16 * 256; i += gs) { histA[i] = 0; histB[i] = 0; }
  for (int i = gid; i < 3 * 16 * 1024; i += gs) cm[i] = 0.f;
  for (int i = gid; i < 3 * 16 * 16; i += gs) peak_cnt[i] = 0;
  for (int i = gid; i < 144; i += gs) done[i] = 0;
  for (int i = gid; i < 48; i += gs) { s1[i] = 0.0; s2[i] = 0.0; }
}

// ---------------------------------------------------------------------------
// K1-S1: circular cross-correlation, fp32 direct, register-tiled.
// Staging via global_load_lds DMA (no VGPR round-trip, no staging ds_writes):
//  - K ring 192 rows: compute window [cph, cph+158] and async-stage target
//    [cph+160, cph+191] are disjoint -> ONE barrier per chunk.
//  - Q double-buffered (2 x 32 rows).
//  - 64KB LDS -> exactly 2 blocks/CU; grid 1024 = 2 uniform residency rounds.
//  - Frees the 16 prefetch VGPRs that previously pushed the FMA loop past the
//    84-VGPR allocation (spill-class VALU traffic ~1:1 with FMAs).
// ---------------------------------------------------------------------------
__launch_bounds__(256, 2)
__global__ void k_corr1(const float* __restrict__ Q, const float* __restrict__ K,
                        float* __restrict__ corr) {
  constexpr int LS = 1024;
  constexpr int LMASK = LS - 1;
  constexpr int NCHUNK = LS / TC;     // 32
  __shared__ float qs[2 * TC * 64];   // 16KB double buffer [buf][t_local][e]
  __shared__ float ks[CAP1 * 64];     // 48KB ring [p][e]; reused for transpose
  const int tid = threadIdx.x;
  const int e = tid & 63;
  const int slot32 = __builtin_amdgcn_readfirstlane((tid >> 6) << 5);
  const int wb = __builtin_amdgcn_readfirstlane((tid >> 6) << 8);  // wave's 4-row LDS float-offset
  const int bh = blockIdx.x;
  const int tau0 = blockIdx.y << 7;         // *128
  const int b = bh >> 3, h = bh & 7;
  const size_t gbase = (size_t)b * L_ * C_ + (size_t)h * 64;
  const int l16 = tid & 15;                 // float4 lane within a 64-e row
  const int rbase = tid >> 4;               // 16 rows per staging iteration
  const int bp0 = 96 - slot32;              // wave-uniform, in {0,32,64,96}

  float acc[32];
#pragma unroll
  for (int i = 0; i < 32; ++i) acc[i] = 0.f;

  // prologue: K logical rows 0..159 at p=l; Q rows 0..31 into qs buf0
#pragma unroll
  for (int it = 0; it < 10; ++it) {
    int l = it * 16 + rbase;
    int tk = (l - tau0 - 127 + 2048) & LMASK;
    gload16(K + gbase + (size_t)tk * C_ + l16 * 4, ks + it * 1024 + wb);
  }
  gload16(Q + gbase + (size_t)rbase * C_ + l16 * 4, qs + wb);
  gload16(Q + gbase + (size_t)(rbase + 16) * C_ + l16 * 4, qs + 1024 + wb);
  __syncthreads();                          // drains vmcnt -> LDS data visible

  int cph = 0;                              // (chunk*32) mod 192
  for (int chunk = 0; chunk < NCHUNK; ++chunk) {
    // ---- issue async staging for chunk+1 (lands during compute) ----------
    if (chunk + 1 < NCHUNK) {
      const int t0n = (chunk + 1) << 5;
      float* qn = qs + ((chunk + 1) & 1) * 2048;
      gload16(Q + gbase + (size_t)(t0n + rbase) * C_ + l16 * 4, qn + wb);
      gload16(Q + gbase + (size_t)(t0n + rbase + 16) * C_ + l16 * 4, qn + 1024 + wb);
      const int l0 = (chunk << 5) + 160;    // logical rows l0..l0+31
      int tk0 = (l0 + rbase - tau0 - 127 + 2048) & LMASK;
      int tk1 = (l0 + rbase + 16 - tau0 - 127 + 2048) & LMASK;
      int p0 = cph + 160; if (p0 >= CAP1) p0 -= CAP1;   // rows 0..15 group base
      int p1 = cph + 176; if (p1 >= CAP1) p1 -= CAP1;   // rows 16..31
      gload16(K + gbase + (size_t)tk0 * C_ + l16 * 4, ks + p0 * 64 + wb);
      gload16(K + gbase + (size_t)tk1 * C_ + l16 * 4, ks + p1 * 64 + wb);
    }
    // ---- compute: two 16x32 register tiles over a 63-reg k-window --------
    const float* qcur = qs + (chunk & 1) * 2048;
    int bp = bp0 + cph; if (bp >= CAP1) bp -= CAP1;     // wave-uniform
    float km[63];
    if (bp <= CAP1 - 47) {
#pragma unroll
      for (int m = 0; m < 47; ++m) km[m] = ks[(bp + m) * 64 + e];
    } else {
#pragma unroll
      for (int m = 0; m < 47; ++m) {
        int p = bp + m; if (p >= CAP1) p -= CAP1;
        km[m] = ks[p * 64 + e];
      }
    }
#pragma unroll
    for (int jt = 0; jt < 16; ++jt) {
      float qv = qcur[jt * 64 + e];
#pragma unroll
      for (int i = 0; i < 32; ++i) acc[i] = fmaf(qv, km[31 + jt - i], acc[i]);
    }
    if (bp <= CAP1 - 63) {
#pragma unroll
      for (int m = 47; m < 63; ++m) km[m] = ks[(bp + m) * 64 + e];
    } else {
#pragma unroll
      for (int m = 47; m < 63; ++m) {
        int p = bp + m; if (p >= CAP1) p -= CAP1;
        km[m] = ks[p * 64 + e];
      }
    }
#pragma unroll
    for (int jt = 16; jt < 32; ++jt) {
      float qv = qcur[jt * 64 + e];
#pragma unroll
      for (int i = 0; i < 32; ++i) acc[i] = fmaf(qv, km[31 + jt - i], acc[i]);
    }
    __syncthreads();    // staged loads landed; window reads done for all waves
    cph += 32; if (cph >= CAP1) cph -= CAP1;
  }
  // transpose in LDS, coalesced write (tau-contiguous rows) ----------------
  float* wt = ks;  // 128*65 = 8320 floats <= 12288
#pragma unroll
  for (int i = 0; i < 32; ++i) wt[(slot32 + i) * 65 + e] = acc[i];
  __syncthreads();
  const int to = tid & 127;
  const size_t cbase = ((size_t)b * C_ + (size_t)h * 64) * LS + tau0 + to;
  for (int cr = tid >> 7; cr < 64; cr += 2)
    corr[cbase + (size_t)cr * LS] = wt[to * 65 + cr];
}

// ---------------------------------------------------------------------------
// K1 (S=2,4): pooled correlation, fp32 direct, register-tiled, circular-K.
// (S==1 path retained but no longer instantiated.)
// ---------------------------------------------------------------------------
template<int S>
__device__ __forceinline__ float4 pool_load(const float* gp) {
  float4 v = *(const float4*)gp;
  if constexpr (S >= 2) {
    float4 v2 = *(const float4*)(gp + C_);
    v.x += v2.x; v.y += v2.y; v.z += v2.z; v.w += v2.w;
  }
  if constexpr (S == 4) {
    float4 v3 = *(const float4*)(gp + 2 * C_);
    float4 v4 = *(const float4*)(gp + 3 * C_);
    v.x += v3.x + v4.x; v.y += v3.y + v4.y;
    v.z += v3.z + v4.z; v.w += v3.w + v4.w;
  }
  constexpr float sc = (S == 1) ? 1.f : (S == 2) ? 0.5f : 0.25f;
  if constexpr (S >= 2) { v.x *= sc; v.y *= sc; v.z *= sc; v.w *= sc; }
  return v;
}

template<int S>
__launch_bounds__(256, 3)
__global__ void k_corr(const float* __restrict__ Q, const float* __restrict__ K,
                       float* __restrict__ corr) {
  constexpr int LS = 1024 / S;
  constexpr int LMASK = LS - 1;
  constexpr int NCHUNK = LS / TC;
  __shared__ float qs[TC * 64];       // 8KB  [t_local][e]
  __shared__ float ks[CAPR * 64];     // 40KB circular [p][e]; reused for transpose
  const int tid = threadIdx.x;
  const int e = tid & 63;
  const int slot32 = __builtin_amdgcn_readfirstlane((tid >> 6) << 5);
  const int bh = blockIdx.x;
  const int tau0 = blockIdx.y << 7;         // *128
  const int b = bh >> 3, h = bh & 7;
  const size_t gbase = (size_t)b * L_ * C_ + (size_t)h * 64;
  const int l16 = tid & 15;                 // float4 lane within a 64-e row
  const int rbase = tid >> 4;               // 16 rows per staging iteration
  const int bp0 = 96 - slot32;              // wave-uniform, in {0,32,64,96}

  float acc[32];
#pragma unroll
  for (int i = 0; i < 32; ++i) acc[i] = 0.f;

  float4 pq0, pq1, pk0, pk1;                // S==1 prefetch registers
  if constexpr (S == 1) {
    pq0 = *(const float4*)(Q + gbase + (size_t)rbase * C_ + l16 * 4);
    pq1 = *(const float4*)(Q + gbase + (size_t)(rbase + 16) * C_ + l16 * 4);
  }

  int cph = 0;                              // (chunk*32) mod 160
  for (int chunk = 0; chunk < NCHUNK; ++chunk) {
    const int t0 = chunk * TC;
    __syncthreads();                        // prev chunk's LDS reads done
    if constexpr (S == 1) {
      *(float4*)(qs + rbase * 64 + l16 * 4) = pq0;
      *(float4*)(qs + (rbase + 16) * 64 + l16 * 4) = pq1;
      if (chunk == 0) {
#pragma unroll
        for (int it = 0; it < 10; ++it) {
          int l = rbase + it * 16;
          int tk = (l - tau0 - 127 + 2048) & LMASK;
          *(float4*)(ks + l * 64 + l16 * 4) =
              *(const float4*)(K + gbase + (size_t)tk * C_ + l16 * 4);
        }
      } else {
        int sp = cph + 128; if (sp >= CAPR) sp -= CAPR;
        int p0 = sp + rbase;      if (p0 >= CAPR) p0 -= CAPR;
        int p1 = sp + rbase + 16; if (p1 >= CAPR) p1 -= CAPR;
        *(float4*)(ks + p0 * 64 + l16 * 4) = pk0;
        *(float4*)(ks + p1 * 64 + l16 * 4) = pk1;
      }
      __syncthreads();
      if (chunk + 1 < NCHUNK) {             // prefetch next chunk
        int t0n = t0 + TC;
        pq0 = *(const float4*)(Q + gbase + (size_t)(t0n + rbase) * C_ + l16 * 4);
        pq1 = *(const float4*)(Q + gbase + (size_t)(t0n + rbase + 16) * C_ + l16 * 4);
        int l0 = t0n + 128 + rbase;
        int tk0 = (l0 - tau0 - 127 + 2048) & LMASK;
        int tk1 = (l0 + 16 - tau0 - 127 + 2048) & LMASK;
        pk0 = *(const float4*)(K + gbase + (size_t)tk0 * C_ + l16 * 4);
        pk1 = *(const float4*)(K + gbase + (size_t)tk1 * C_ + l16 * 4);
      }
    } else {
      // stage q: 32 rows
#pragma unroll
      for (int it = 0; it < 2; ++it) {
        int row = rbase + it * 16;
        int traw = (t0 + row) * S;
        float4 v = pool_load<S>(Q + gbase + (size_t)traw * C_ + l16 * 4);
        *(float4*)(qs + row * 64 + l16 * 4) = v;
      }
      if (chunk == 0) {
#pragma unroll
        for (int it = 0; it < 10; ++it) {
          int l = rbase + it * 16;
          int tk = (l - tau0 - 127 + 2048) & LMASK;
          float4 v = pool_load<S>(K + gbase + (size_t)tk * S * C_ + l16 * 4);
          *(float4*)(ks + l * 64 + l16 * 4) = v;
        }
      } else {
        int sp = cph + 128; if (sp >= CAPR) sp -= CAPR;
#pragma unroll
        for (int it = 0; it < 2; ++it) {
          int row = rbase + it * 16;
          int l = t0 + 128 + row;
          int tk = (l - tau0 - 127 + 2048) & LMASK;
          int p = sp + row; if (p >= CAPR) p -= CAPR;
          float4 v = pool_load<S>(K + gbase + (size_t)tk * S * C_ + l16 * 4);
          *(float4*)(ks + p * 64 + l16 * 4) = v;
        }
      }
      __syncthreads();
    }
    // ---- compute: two 16x32 register tiles over a 63-reg k-window
    int bp = bp0 + cph; if (bp >= CAPR) bp -= CAPR;   // wave-uniform
    float km[63];
    if (bp <= CAPR - 47) {
#pragma unroll
      for (int m = 0; m < 47; ++m) km[m] = ks[(bp + m) * 64 + e];
    } else {
#pragma unroll
      for (int m = 0; m < 47; ++m) {
        int p = bp + m; if (p >= CAPR) p -= CAPR;
        km[m] = ks[p * 64 + e];
      }
    }
#pragma unroll
    for (int jt = 0; jt < 16; ++jt) {
      float qv = qs[jt * 64 + e];
#pragma unroll
      for (int i = 0; i < 32; ++i) acc[i] = fmaf(qv, km[31 + jt - i], acc[i]);
    }
    if (bp <= CAPR - 63) {
#pragma unroll
      for (int m = 47; m < 63; ++m) km[m] = ks[(bp + m) * 64 + e];
    } else {
#pragma unroll
      for (int m = 47; m < 63; ++m) {
        int p = bp + m; if (p >= CAPR) p -= CAPR;
        km[m] = ks[p * 64 + e];
      }
    }
#pragma unroll
    for (int jt = 16; jt < 32; ++jt) {
      float qv = qs[jt * 64 + e];
#pragma unroll
      for (int i = 0; i < 32; ++i) acc[i] = fmaf(qv, km[31 + jt - i], acc[i]);
    }
    cph += 32; if (cph >= CAPR) cph -= CAPR;
  }
  // transpose in LDS, coalesced write (tau-contiguous rows) ----------------
  __syncthreads();
  float* wt = ks;  // 128*65 = 8320 floats <= 10240
#pragma unroll
  for (int i = 0; i < 32; ++i) wt[(slot32 + i) * 65 + e] = acc[i];
  __syncthreads();
  const int to = tid & 127;
  const size_t cbase = ((size_t)b * C_ + (size_t)h * 64) * LS + tau0 + to;
  for (int cr = tid >> 7; cr < 64; cr += 2)
    corr[cbase + (size_t)cr * LS] = wt[to * 65 + cr];
}

// ---------------------------------------------------------------------------
// K2 (merged scales): per-(scale,b) stats, cm partials, peak detect +
// compaction (one global atomic per block) + level-0 histogram.
// Grid: (C_/GCH, B, 3).
// ---------------------------------------------------------------------------
__launch_bounds__(256, 4)
__global__ void k_stats(const float* __restrict__ corrbase, float* __restrict__ cm,
                        double* s1, double* s2, u32* peak_cnt, u32* histA,
                        u32* pkbase) {
  __shared__ __align__(16) float rows[GCH * 1024];
  __shared__ u32 hist_s[256];
  __shared__ double red_d[8];
  __shared__ u32 wv[4], wbase[4];
  const int tid = threadIdx.x;
  const int sidx = blockIdx.z;
  const int b = blockIdx.y;
  const int sb = sidx * 16 + b;
  const int Ls = 1024 >> sidx;
  const int c0 = blockIdx.x * GCH;
  const int lane = tid & 63;
  const int wave = tid >> 6;
  hist_s[tid] = 0;
  {
    const float4* src4 =
        (const float4*)(corrbase + co(sidx) + ((size_t)b * C_ + c0) * Ls);
    float4* dst4 = (float4*)rows;
    const int n4 = GCH * Ls / 4;
    for (int i = tid; i < n4; i += 256) dst4[i] = src4[i];
  }
  __syncthreads();
  const int nt = Ls >> 8;         // taus per thread: 4/2/1
  float cmacc[4] = {0.f, 0.f, 0.f, 0.f};
  double ls1 = 0.0, ls2 = 0.0;
  u32 mycnt = 0;
  // ---- phase 1: stats + peak count + level-0 hist
  for (int g = 0; g < GCH; ++g) {
    const float* row = rows + g * Ls;
    for (int i = 0; i < nt; ++i) {
      int t = tid + (i << 8);
      float v = row[t];
      cmacc[i] += v;
      ls1 += (double)v;
      ls2 += (double)v * (double)v;
      bool pk = (t >= 1) && (t <= Ls - 2) && (v > row[t - 1]) && (v > row[t + 1]);
      if (pk) {
        ++mycnt;
        atomicAdd(&hist_s[f2key(v) >> 24], 1u);
      }
    }
  }
  // block-scan peak counts -> single global atomic for base
  u32 wc = mycnt;
  for (int off = 32; off; off >>= 1) wc += __shfl_down(wc, off, 64);
  if (lane == 0) wv[wave] = wc;
  __syncthreads();
  if (tid == 0) {
    u32 t = 0;
    for (int w = 0; w < 4; ++w) { wbase[w] = t; t += wv[w]; }
    u32 base = atomicAdd(&peak_cnt[sb * 16], t);
    for (int w = 0; w < 4; ++w) wbase[w] += base;
  }
  __syncthreads();
  // ---- phase 2: re-detect, compacted write at deterministic offsets
  const u32 cap = pk_cap(sidx);
  u32* dst_pk = pkbase + pk_off(sidx) + (u32)b * cap;
  u32 off_w = wbase[wave];
  const u64 below = (1ull << lane) - 1ull;
  for (int g = 0; g < GCH; ++g) {
    const float* row = rows + g * Ls;
    for (int i = 0; i < nt; ++i) {
      int t = tid + (i << 8);
      float v = row[t];
      bool pk = (t >= 1) && (t <= Ls - 2) && (v > row[t - 1]) && (v > row[t + 1]);
      u64 mask = __ballot(pk);
      if (pk) {
        u32 idx = off_w + (u32)__popcll(mask & below);
        if (idx < cap) dst_pk[idx] = f2key(v);
      }
      off_w += (u32)__popcll(mask);
    }
  }
  // cm partials: one unsafe float atomic per owned tau
  for (int i = 0; i < nt; ++i) {
    int t = tid + (i << 8);
    unsafeAtomicAdd(&cm[sb * 1024 + t], cmacc[i]);
  }
  // s1/s2: wave reduce -> block reduce -> one double atomic per block
  for (int off = 32; off; off >>= 1) {
    ls1 += __shfl_down(ls1, off, 64);
    ls2 += __shfl_down(ls2, off, 64);
  }
  if (lane == 0) { red_d[wave] = ls1; red_d[4 + wave] = ls2; }
  __syncthreads();
  if (tid == 0) {
    unsafeAtomicAdd(&s1[sb], red_d[0] + red_d[1] + red_d[2] + red_d[3]);
    unsafeAtomicAdd(&s2[sb], red_d[4] + red_d[5] + red_d[6] + red_d[7]);
  }
  if (hist_s[tid]) atomicAdd(&histA[sb * 256 + tid], hist_s[tid]);
}

// ---------------------------------------------------------------------------
// K3 (merged): one block per (scale,b). cm pk-count, MLP -> kvals, level-0
// radix scan (snapshot-then-write). Energy computed redundantly per block.
// ---------------------------------------------------------------------------
__global__ void k_mlp(const float* __restrict__ cm, const double* s1,
                      const double* s2, const u32* peak_cnt, const u32* histA,
                      int* rank_s, u32* prefix_s, u32* active, float* thresh,
                      const float* w1, const float* b1, const float* w2,
                      const float* b2, const float* w3, const float* b3) {
  __shared__ float wls[673];       // w1(96) b1(32) w2(512) b2(16) w3(16) b3(1)
  __shared__ float cmrow[1024];
  __shared__ int red_i[4];
  __shared__ u32 cum[256];
  const int tid = threadIdx.x;
  const int sb = blockIdx.x;
  const int sidx = sb >> 4;
  const int Ls = 1024 >> sidx;
  for (int i = tid; i < 96; i += 256) wls[i] = w1[i];
  for (int i = tid; i < 32; i += 256) wls[96 + i] = b1[i];
  for (int i = tid; i < 512; i += 256) wls[128 + i] = w2[i];
  if (tid < 16) wls[640 + tid] = b2[tid];
  if (tid < 16) wls[656 + tid] = w3[tid];
  if (tid == 0) wls[672] = b3[0];
  for (int i = tid; i < Ls; i += 256) cmrow[i] = cm[sb * 1024 + i];
  __syncthreads();
  int cnt = 0;
  for (int t = 1 + tid; t <= Ls - 2; t += 256) {
    float v = cmrow[t];
    cnt += (v > cmrow[t - 1]) && (v > cmrow[t + 1]);
  }
  for (int off = 32; off; off >>= 1) cnt += __shfl_down(cnt, off, 64);
  if ((tid & 63) == 0) red_i[tid >> 6] = cnt;
  __syncthreads();
  if (tid == 0) {
    double tot = 0.0;
    for (int j = 0; j < 16; ++j) tot += s2[sidx * 16 + j];
    float f0 = (float)(tot / (16.0 * (double)Ls));
    double N = (double)C_ * (double)Ls;
    float f1 = (float)((s2[sb] - s1[sb] * s1[sb] / N) / (N - 1.0));
    float f2 = (float)(red_i[0] + red_i[1] + red_i[2] + red_i[3]);
    float h1[32];
    for (int j = 0; j < 32; ++j)
      h1[j] = fmaxf(0.f, wls[j * 3] * f0 + wls[j * 3 + 1] * f1 + wls[j * 3 + 2] * f2 + wls[96 + j]);
    float h2[16];
    for (int j = 0; j < 16; ++j) {
      float a = wls[640 + j];
      for (int i = 0; i < 32; ++i) a += wls[128 + j * 32 + i] * h1[i];
      h2[j] = fmaxf(0.f, a);
    }
    float z = wls[672];
    for (int i = 0; i < 16; ++i) z += wls[656 + i] * h2[i];
    float ratio = 1.0f / (1.0f + __expf(-z));
    int kv = (int)(ratio * (float)Ls);
    kv = min(max(kv, 1), Ls);
    int cntb = (int)peak_cnt[sb * 16];
    active[sb] = (u32)(cntb > kv);
    thresh[sb] = -INFINITY;
    rank_s[sb] = kv;
    prefix_s[sb] = 0;
  }
  __syncthreads();
  // level-0 radix scan: parallel suffix-scan over 256 bins
  cum[tid] = histA[sb * 256 + tid];
  __syncthreads();
  for (int off = 1; off < 256; off <<= 1) {
    u32 add = (tid + off < 256) ? cum[tid + off] : 0u;
    __syncthreads();
    cum[tid] += add;
    __syncthreads();
  }
  u32 act_b = active[sb];
  u32 r = act_b ? (u32)rank_s[sb] : 0u;
  u32 cc = cum[tid];
  u32 cnext = (tid == 255) ? 0u : cum[tid + 1];
  __syncthreads();          // all snapshots done before any write
  if (act_b && r > 0 && cc >= r && cnext < r) {
    prefix_s[sb] = (u32)tid << 24;
    rank_s[sb] = (int)(r - cnext);
  }
}

// ---------------------------------------------------------------------------
// K_sel (levels 1..3): full key scan, LDS->global hist, ticket finisher does
// the parallel suffix-scan + snapshot-write refine. Grid: 3*16*NB_SEL.
// ---------------------------------------------------------------------------
__global__ void k_sel(const u32* __restrict__ pkbase, const u32* peak_cnt,
                      const u32* active, int* rank_s, u32* prefix_s,
                      u32* hist, u32* done, float* thresh, int level) {
  __shared__ u32 hist_s[256];
  __shared__ u32 cum[256];
  __shared__ u32 islast;
  const int tid = threadIdx.x;
  const int sb = blockIdx.x / NB_SEL;
  const int blk = blockIdx.x % NB_SEL;
  const int sidx = sb >> 4;
  hist_s[tid] = 0;
  if (tid == 0) islast = 0;
  __syncthreads();
  const int act = (int)active[sb];
  const u32 cap = pk_cap(sidx);
  u32 cnt = peak_cnt[sb * 16];
  if (cnt > cap) cnt = cap;
  if (act) {
    const u32 pref = prefix_s[sb];
    const int hi_sh = 32 - 8 * level;
    const int b_sh = 24 - 8 * level;
    const u32 lo = (u32)(((u64)cnt * (u64)blk) / NB_SEL);
    const u32 hi = (u32)(((u64)cnt * (u64)(blk + 1)) / NB_SEL);
    const u32* src = pkbase + pk_off(sidx) + (u32)(sb & 15) * cap;
    for (u32 i = lo + tid; i < hi; i += 256) {
      u32 key = src[i];
      if ((key >> hi_sh) == (pref >> hi_sh))
        atomicAdd(&hist_s[(key >> b_sh) & 255u], 1u);
    }
  }
  __syncthreads();
  if (hist_s[tid]) atomicAdd(&hist[sb * 256 + tid], hist_s[tid]);
  __syncthreads();                        // barrier drains all vmem (vmcnt(0))
  if (tid == 0) {
    __threadfence();
    u32 t = atomicAdd(&done[(level - 1) * 48 + sb], 1u);
    if (t == NB_SEL - 1) islast = 1;
  }
  __syncthreads();
  if (!islast) return;
  // ---- finisher (exactly one block per (scale,b))
  __threadfence();
  u32 hv = atomicAdd(&hist[sb * 256 + tid], 0u);    // atomic read
  cum[tid] = hv;
  hist[sb * 256 + tid] = 0;               // ready for next level
  __syncthreads();
  for (int off = 1; off < 256; off <<= 1) {
    u32 add = (tid + off < 256) ? cum[tid + off] : 0u;
    __syncthreads();
    cum[tid] += add;
    __syncthreads();
  }
  u32 r = act ? (u32)rank_s[sb] : 0u;
  u32 pref2 = act ? prefix_s[sb] : 0u;
  u32 cc = cum[tid];
  u32 cnext = (tid == 255) ? 0u : cum[tid + 1];
  __syncthreads();                        // snapshots before write
  if (act && r > 0 && cc >= r && cnext < r) {
    u32 np = pref2 | ((u32)tid << (24 - 8 * level));
    prefix_s[sb] = np;
    rank_s[sb] = (int)(r - cnext);
    if (level == 3) thresh[sb] = key2f(np);
  }
}

// ---------------------------------------------------------------------------
// K5a (merged): per-(scale,b,c) softmax stats. Grid: (8192, 3).
// ---------------------------------------------------------------------------
__global__ void k_softstats(const float* __restrict__ corrbase, const float* thresh,
                            float2* __restrict__ mZ) {
  __shared__ float row[1024];
  __shared__ float red_s[8];
  const int tid = threadIdx.x;
  const int bc = blockIdx.x;
  const int sidx = blockIdx.y;
  const int Ls = 1024 >> sidx;
  const float th = thresh[sidx * 16 + (bc >> 9)];
  const float* src = corrbase + co(sidx) + (size_t)bc * Ls;
  for (int t = tid; t < Ls; t += 256) row[t] = src[t];
  __syncthreads();
  float mx = 0.f;   // zeros always present in attn row -> true max >= 0
  for (int t = tid; t < Ls; t += 256) {
    float v = row[t];
    bool pk = (t >= 1) && (t <= Ls - 2) && (v > row[t - 1]) && (v > row[t + 1]) && (v >= th);
    if (pk) mx = fmaxf(mx, v);
  }
  for (int off = 32; off; off >>= 1) mx = fmaxf(mx, __shfl_down(mx, off, 64));
  if ((tid & 63) == 0) red_s[tid >> 6] = mx;
  __syncthreads();
  float m = fmaxf(fmaxf(red_s[0], red_s[1]), fmaxf(red_s[2], red_s[3]));
  float zs = 0.f;
  for (int t = tid; t < Ls; t += 256) {
    float v = row[t];
    bool pk = (t >= 1) && (t <= Ls - 2) && (v > row[t - 1]) && (v > row[t + 1]) && (v >= th);
    float a = pk ? v : 0.f;
    zs += __expf(a - m);
  }
  for (int off = 32; off; off >>= 1) zs += __shfl_down(zs, off, 64);
  if ((tid & 63) == 0) red_s[4 + (tid >> 6)] = zs;
  __syncthreads();
  if (tid == 0) {
    float Z = red_s[4] + red_s[5] + red_s[6] + red_s[7];
    mZ[sidx * 8192 + bc] = make_float2(m, 1.0f / Z);
  }
}

// ---------------------------------------------------------------------------
// K5b (s=2,4): o_s[b][tau][c] = softmax-weight * pooled v. 128-tau tiles.
// corr/mZ/thresh passed pre-offset for the scale.
// ---------------------------------------------------------------------------
__launch_bounds__(256, 4)
__global__ void k_apply(const float* __restrict__ corr, const float* __restrict__ V,
                        const float2* __restrict__ mZ, const float* thresh,
                        float* __restrict__ o, int Ls, int s) {
  __shared__ float ct[64][131];      // col j holds t = t0-1+j (clamped)
  __shared__ float m_s[64], rz_s[64];
  const int tid = threadIdx.x;
  const int b = blockIdx.z;
  const int c0 = blockIdx.y << 6;
  const int t0 = blockIdx.x << 7;
  {
    const int row0 = tid >> 7, jc = tid & 127;
    for (int rr = row0; rr < 64; rr += 2) {
      const float* src = corr + ((size_t)b * C_ + c0 + rr) * Ls;
      for (int j = jc; j < 130; j += 128) {
        int t = t0 - 1 + j;
        t = max(0, min(t, Ls - 1));
        ct[rr][j] = src[t];
      }
    }
  }
  if (tid < 64) {
    float2 v = mZ[b * C_ + c0 + tid];
    m_s[tid] = v.x; rz_s[tid] = v.y;
  }
  __syncthreads();
  const float th = thresh[b];
  const int cl = tid & 63, ts = tid >> 6;
  for (int ii = 0; ii < 32; ++ii) {
    int tl = ts + (ii << 2);
    int tg = t0 + tl;
    float vm = ct[cl][tl], vc = ct[cl][tl + 1], vp = ct[cl][tl + 2];
    bool pk = (tg >= 1) && (tg <= Ls - 2) && (vc > vm) && (vc > vp) && (vc >= th);
    float a = pk ? vc : 0.f;
    float w = __expf(a - m_s[cl]) * rz_s[cl];
    size_t vb = ((size_t)b * L_ + (size_t)tg * s) * C_ + c0 + cl;
    float vv;
    if (s == 2) vv = (V[vb] + V[vb + C_]) * 0.5f;
    else vv = ((V[vb] + V[vb + C_]) + (V[vb + 2 * C_] + V[vb + 3 * C_])) * 0.25f;
    o[((size_t)b * Ls + tg) * C_ + c0 + cl] = w * vv;
  }
}

// ---------------------------------------------------------------------------
// K5b-final (s=1): out = sw0*w*v + sw1*lerp(o2) + sw2*lerp(o4). 128-tau tiles.
// ---------------------------------------------------------------------------
__launch_bounds__(256, 4)
__global__ void k_apply_final(const float* __restrict__ corr, const float* __restrict__ V,
                              const float2* __restrict__ mZ, const float* thresh,
                              const float* __restrict__ o2, const float* __restrict__ o4,
                              const float* __restrict__ sw, float* __restrict__ out) {
  __shared__ float ct[64][131];
  __shared__ float m_s[64], rz_s[64];
  const int Ls = 1024;
  const int tid = threadIdx.x;
  const int b = blockIdx.z;
  const int c0 = blockIdx.y << 6;
  const int t0 = blockIdx.x << 7;
  {
    const int row0 = tid >> 7, jc = tid & 127;
    for (int rr = row0; rr < 64; rr += 2) {
      const float* src = corr + ((size_t)b * C_ + c0 + rr) * Ls;
      for (int j = jc; j < 130; j += 128) {
        int t = t0 - 1 + j;
        t = max(0, min(t, Ls - 1));
        ct[rr][j] = src[t];
      }
    }
  }
  if (tid < 64) {
    float2 v = mZ[b * C_ + c0 + tid];
    m_s[tid] = v.x; rz_s[tid] = v.y;
  }
  __syncthreads();
  const float th = thresh[b];
  const float sw0 = sw[0], sw1 = sw[1], sw2 = sw[2];
  const int cl = tid & 63, ts = tid >> 6;
  for (int ii = 0; ii < 32; ++ii) {
    int tl = ts + (ii << 2);
    int tg = t0 + tl;
    float vm = ct[cl][tl], vc = ct[cl][tl + 1], vp = ct[cl][tl + 2];
    bool pk = (tg >= 1) && (tg <= Ls - 2) && (vc > vm) && (vc > vp) && (vc >= th);
    float a = pk ? vc : 0.f;
    float w = __expf(a - m_s[cl]) * rz_s[cl];
    float v1 = V[((size_t)b * L_ + tg) * C_ + c0 + cl];
    float r = sw0 * w * v1;
    {
      float srcp = fmaxf((tg + 0.5f) * 0.5f - 0.5f, 0.f);
      int x0 = (int)srcp;
      float lam = srcp - (float)x0;
      int x1 = min(x0 + 1, 511);
      const float* p = o2 + (size_t)b * 512 * C_ + c0 + cl;
      r += sw1 * ((1.f - lam) * p[(size_t)x0 * C_] + lam * p[(size_t)x1 * C_]);
    }
    {
      float srcp = fmaxf((tg + 0.5f) * 0.25f - 0.5f, 0.f);
      int x0 = (int)srcp;
      float lam = srcp - (float)x0;
      int x1 = min(x0 + 1, 255);
      const float* p = o4 + (size_t)b * 256 * C_ + c0 + cl;
      r += sw2 * ((1.f - lam) * p[(size_t)x0 * C_] + lam * p[(size_t)x1 * C_]);
    }
    out[((size_t)b * L_ + tg) * C_ + c0 + cl] = r;
  }
}

// ---------------------------------------------------------------------------
extern "C" void kernel_launch(void* const* d_in, const int* in_sizes, int n_in,
                              void* d_out, int out_size, void* d_ws, size_t ws_size,
                              hipStream_t stream) {
  const float* Q  = (const float*)d_in[0];
  const float* Kk = (const float*)d_in[1];
  const float* V  = (const float*)d_in[2];
  const float* sw = (const float*)d_in[3];
  const float* w1 = (const float*)d_in[4];
  const float* b1 = (const float*)d_in[5];
  const float* w2 = (const float*)d_in[6];
  const float* b2 = (const float*)d_in[7];
  const float* w3 = (const float*)d_in[8];
  const float* b3 = (const float*)d_in[9];
  float* out = (float*)d_out;

  char* ws = (char*)d_ws;
  size_t p = 0;
  auto alloc = [&](size_t n) { char* r = ws + p; p = (p + n + 255) & ~(size_t)255; return r; };
  // corr for all 3 scales: [s1 | s2 | s4], elem offsets 0 / 8388608 / 12582912
  float*  corr = (float*)alloc((size_t)(8388608 + 4194304 + 2097152) * 4);  // 58.7 MB
  // o-region: o2 (16.8MB) + o4 (8.4MB); pk_buf (22.5MB) aliases it (pk dies
  // after k_sel level 3; o2/o4 born at k_apply, strictly later in-stream).
  char*   oreg = alloc((size_t)25165824);
  float*  o2   = (float*)oreg;
  float*  o4   = (float*)(oreg + 16777216);
  u32*    pk   = (u32*)oreg;
  float*  cm       = (float*)alloc(3 * 16 * 1024 * 4);
  float2* mZ       = (float2*)alloc(3 * 16 * 512 * 8);
  double* s1d      = (double*)alloc(48 * 8);
  double* s2d      = (double*)alloc(48 * 8);
  u32*    histA    = (u32*)alloc(3 * 16 * 256 * 4);
  u32*    histB    = (u32*)alloc(3 * 16 * 256 * 4);
  u32*    peak_cnt = (u32*)alloc(3 * 16 * 16 * 4);   // padded: 1 counter / 64B
  u32*    done     = (u32*)alloc(144 * 4);
  int*    rank_s   = (int*)alloc(48 * 4);
  u32*    prefix_s = (u32*)alloc(48 * 4);
  u32*    active   = (u32*)alloc(48 * 4);
  float*  thresh   = (float*)alloc(48 * 4);

  k_init<<<dim3(16), dim3(256), 0, stream>>>(histA, histB, peak_cnt, done,
                                             s1d, s2d, cm);
  k_corr1<<<dim3(128, 8), dim3(256), 0, stream>>>(Q, Kk, corr);
  k_corr<2><<<dim3(128, 4), dim3(256), 0, stream>>>(Q, Kk, corr + 8388608);
  k_corr<4><<<dim3(128, 2), dim3(256), 0, stream>>>(Q, Kk, corr + 12582912);
  k_stats<<<dim3(C_ / GCH, B_, 3), dim3(256), 0, stream>>>(
      corr, cm, s1d, s2d, peak_cnt, histA, pk);
  k_mlp<<<dim3(48), dim3(256), 0, stream>>>(
      cm, s1d, s2d, peak_cnt, histA, rank_s, prefix_s, active, thresh,
      w1, b1, w2, b2, w3, b3);
  for (int level = 1; level <= 3; ++level)
    k_sel<<<dim3(48 * NB_SEL), dim3(256), 0, stream>>>(
        pk, peak_cnt, active, rank_s, prefix_s, histB, done, thresh, level);
  k_softstats<<<dim3(8192, 3), dim3(256), 0, stream>>>(corr, thresh, mZ);
  k_apply<<<dim3(2, 8, 16), dim3(256), 0, stream>>>(
      corr + 12582912, V, mZ + 2 * 8192, thresh + 32, o4, 256, 4);
  k_apply<<<dim3(4, 8, 16), dim3(256), 0, stream>>>(
      corr + 8388608, V, mZ + 1 * 8192, thresh + 16, o2, 512, 2);
  k_apply_final<<<dim3(8, 8, 16), dim3(256), 0, stream>>>(
      corr, V, mZ, thresh, o2, o4, sw, out);
}

// Round 2
// 790.480 us; speedup vs baseline: 1.0115x; 1.0097x over previous
//
#include <hip/hip_runtime.h>
#include <math.h>

typedef unsigned int u32;
typedef unsigned long long u64;

#define B_ 16
#define L_ 1024
#define H_ 8
#define E_ 64
#define C_ 512            // H_*E_
#define NB_SEL 8          // blocks per (scale,b) in k_sel
#define GCH 8             // channels per k_stats block
#define TC 32             // k_corr time-chunk
#define CAPR 160          // k_corr<S> circular K-buffer rows (= 127 + TC + 1)
#define CAP1 192          // k_corr1 ring rows: 127 hist + 32 cur + 32 async-stage

// scale indexing: sidx 0 -> s=1 (Ls=1024), 1 -> s=2 (512), 2 -> s=4 (256)
__device__ __forceinline__ size_t co(int sidx) {       // corr elem offset
  return sidx == 0 ? 0u : (sidx == 1 ? 8388608u : 12582912u);
}
__device__ __forceinline__ u32 pk_off(int sidx) {      // pk elem offset in o-region
  return sidx == 0 ? 0u : (sidx == 1 ? 3211264u : 4816896u);
}
__device__ __forceinline__ u32 pk_cap(int sidx) { return 200704u >> sidx; }

__device__ __forceinline__ u32 f2key(float f) {
  u32 u = __float_as_uint(f);
  return (u & 0x80000000u) ? ~u : (u | 0x80000000u);
}
__device__ __forceinline__ float key2f(u32 k) {
  u32 u = (k & 0x80000000u) ? (k ^ 0x80000000u) : ~k;
  return __uint_as_float(u);
}

// direct global->LDS DMA, 16B/lane; LDS dest = wave-uniform base + lane*16
using u32g = __attribute__((address_space(1))) const unsigned int;
using u32l = __attribute__((address_space(3))) unsigned int;
__device__ __forceinline__ void gload16(const float* g, float* l) {
  __builtin_amdgcn_global_load_lds((u32g*)g, (u32l*)l, 16, 0, 0);
}

// ---------------------------------------------------------------------------
// K_init: zero control state once (single-pass pipeline -> no mid-run resets)
// ---------------------------------------------------------------------------
__global__ void k_init(u32* histA, u32* histB, u32* peak_cnt, u32* done,
                       double* s1, double* s2, float* cm) {
  const int gid = blockIdx.x * 256 + threadIdx.x;
  const int gs = gridDim.x * 256;
  for (int i = gid; i < 3 * 16 * 256; i += gs) { histA[i] = 0; histB[i] = 0; }
  for (int i = gid; i < 3 * 16 * 1024; i += gs) cm[i] = 0.f;
  for (int i = gid; i < 3 * 16 * 16; i += gs) peak_cnt[i] = 0;
  for (int i = gid; i < 144; i += gs) done[i] = 0;
  for (int i = gid; i < 48; i += gs) { s1[i] = 0.0; s2[i] = 0.0; }
}

// ---------------------------------------------------------------------------
// K1-S1: circular cross-correlation, fp32 direct, register-tiled.
// 512 threads / 8 waves, 16 taus per wave:
//  - acc[16] + km live<=31 -> ~56 VGPR (was 88 at the allocator wall)
//  - LDS 64KB (ring 192 + Q dbuf) unchanged -> 2 blocks/CU -> 16 waves/CU
//    = 4 waves/SIMD (was 2): latency hiding doubles at same FMA-issue floor.
//  - staging: 8 waves x 4 rows = 32 rows per global_load_lds pass; stage
//    region [cph+160,cph+192) is 32-aligned -> never wraps mid-wave.
//  - ONE barrier per chunk (stage target disjoint from compute window).
// ---------------------------------------------------------------------------
__launch_bounds__(512, 4)
__global__ void k_corr1(const float* __restrict__ Q, const float* __restrict__ K,
                        float* __restrict__ corr) {
  constexpr int LS = 1024;
  constexpr int LMASK = LS - 1;
  constexpr int NCHUNK = LS / TC;     // 32
  __shared__ float qs[2 * TC * 64];   // 16KB double buffer [buf][t_local][e]
  __shared__ float ks[CAP1 * 64];     // 48KB ring [p][e]; reused for transpose
  const int tid = threadIdx.x;        // 0..511
  const int e = tid & 63;
  const int slot16 = __builtin_amdgcn_readfirstlane((tid >> 6) << 4); // wave*16
  const int wb = __builtin_amdgcn_readfirstlane((tid >> 6) << 8);     // wave*256 floats (4 rows)
  const int bh = blockIdx.x;
  const int tau0 = blockIdx.y << 7;         // *128
  const int b = bh >> 3, h = bh & 7;
  const size_t gbase = (size_t)b * L_ * C_ + (size_t)h * 64;
  const int l16 = tid & 15;                 // float4 lane within a 64-e row
  const int rbase = tid >> 4;               // 0..31: row within a 32-row pass
  const int bp0 = 112 - slot16;             // wave-uniform (SGPR), in {0,16,...,112}

  float acc[16];
#pragma unroll
  for (int i = 0; i < 16; ++i) acc[i] = 0.f;

  // prologue: K logical rows 0..159 (5 passes of 32); Q rows 0..31 into buf0
#pragma unroll
  for (int it = 0; it < 5; ++it) {
    int l = it * 32 + rbase;
    int tk = (l - tau0 - 127 + 2048) & LMASK;
    gload16(K + gbase + (size_t)tk * C_ + l16 * 4, ks + it * 2048 + wb);
  }
  gload16(Q + gbase + (size_t)rbase * C_ + l16 * 4, qs + wb);
  __syncthreads();                          // drains vmcnt -> LDS data visible

  int cph = 0;                              // (chunk*32) mod 192
  for (int chunk = 0; chunk < NCHUNK; ++chunk) {
    // ---- issue async staging for chunk+1 (lands during compute) ----------
    if (chunk + 1 < NCHUNK) {
      const int t0n = (chunk + 1) << 5;
      float* qn = qs + ((chunk + 1) & 1) * 2048;
      gload16(Q + gbase + (size_t)(t0n + rbase) * C_ + l16 * 4, qn + wb);
      const int l0 = (chunk << 5) + 160;    // logical rows l0..l0+31
      int tk = (l0 + rbase - tau0 - 127 + 2048) & LMASK;
      int sp = cph + 160; if (sp >= CAP1) sp -= CAP1;  // 32-aligned, contiguous
      gload16(K + gbase + (size_t)tk * C_ + l16 * 4, ks + sp * 64 + wb);
    }
    // ---- compute: two 16x16 register tiles over a 47-reg k-window --------
    const float* qcur = qs + (chunk & 1) * 2048;
    int bp = bp0 + cph; if (bp >= CAP1) bp -= CAP1;     // wave-uniform (SGPR)
    float km[47];
    if (bp <= CAP1 - 31) {
#pragma unroll
      for (int m = 0; m < 31; ++m) km[m] = ks[(bp + m) * 64 + e];
    } else {
#pragma unroll
      for (int m = 0; m < 31; ++m) {
        int p = bp + m; if (p >= CAP1) p -= CAP1;
        km[m] = ks[p * 64 + e];
      }
    }
#pragma unroll
    for (int jt = 0; jt < 16; ++jt) {
      float qv = qcur[jt * 64 + e];
#pragma unroll
      for (int i = 0; i < 16; ++i) acc[i] = fmaf(qv, km[15 + jt - i], acc[i]);
    }
    if (bp <= CAP1 - 47) {
#pragma unroll
      for (int m = 31; m < 47; ++m) km[m] = ks[(bp + m) * 64 + e];
    } else {
#pragma unroll
      for (int m = 31; m < 47; ++m) {
        int p = bp + m; if (p >= CAP1) p -= CAP1;
        km[m] = ks[p * 64 + e];
      }
    }
#pragma unroll
    for (int jt = 16; jt < 32; ++jt) {
      float qv = qcur[jt * 64 + e];
#pragma unroll
      for (int i = 0; i < 16; ++i) acc[i] = fmaf(qv, km[15 + jt - i], acc[i]);
    }
    __syncthreads();    // staged loads landed; window reads done for all waves
    cph += 32; if (cph >= CAP1) cph -= CAP1;
  }
  // transpose in LDS, coalesced write (tau-contiguous rows) ----------------
  float* wt = ks;  // 128*65 = 8320 floats <= 12288
#pragma unroll
  for (int i = 0; i < 16; ++i) wt[(slot16 + i) * 65 + e] = acc[i];
  __syncthreads();
  const int to = tid & 127;
  const size_t cbase = ((size_t)b * C_ + (size_t)h * 64) * LS + tau0 + to;
  for (int cr = tid >> 7; cr < 64; cr += 4)
    corr[cbase + (size_t)cr * LS] = wt[to * 65 + cr];
}

// ---------------------------------------------------------------------------
// K1 (S=2,4): pooled correlation, fp32 direct, register-tiled, circular-K.
// ---------------------------------------------------------------------------
template<int S>
__device__ __forceinline__ float4 pool_load(const float* gp) {
  float4 v = *(const float4*)gp;
  if constexpr (S >= 2) {
    float4 v2 = *(const float4*)(gp + C_);
    v.x += v2.x; v.y += v2.y; v.z += v2.z; v.w += v2.w;
  }
  if constexpr (S == 4) {
    float4 v3 = *(const float4*)(gp + 2 * C_);
    float4 v4 = *(const float4*)(gp + 3 * C_);
    v.x += v3.x + v4.x; v.y += v3.y + v4.y;
    v.z += v3.z + v4.z; v.w += v3.w + v4.w;
  }
  constexpr float sc = (S == 1) ? 1.f : (S == 2) ? 0.5f : 0.25f;
  if constexpr (S >= 2) { v.x *= sc; v.y *= sc; v.z *= sc; v.w *= sc; }
  return v;
}

template<int S>
__launch_bounds__(256, 3)
__global__ void k_corr(const float* __restrict__ Q, const float* __restrict__ K,
                       float* __restrict__ corr) {
  constexpr int LS = 1024 / S;
  constexpr int LMASK = LS - 1;
  constexpr int NCHUNK = LS / TC;
  __shared__ float qs[TC * 64];       // 8KB  [t_local][e]
  __shared__ float ks[CAPR * 64];     // 40KB circular [p][e]; reused for transpose
  const int tid = threadIdx.x;
  const int e = tid & 63;
  const int slot32 = __builtin_amdgcn_readfirstlane((tid >> 6) << 5);
  const int bh = blockIdx.x;
  const int tau0 = blockIdx.y << 7;         // *128
  const int b = bh >> 3, h = bh & 7;
  const size_t gbase = (size_t)b * L_ * C_ + (size_t)h * 64;
  const int l16 = tid & 15;                 // float4 lane within a 64-e row
  const int rbase = tid >> 4;               // 16 rows per staging iteration
  const int bp0 = 96 - slot32;              // wave-uniform, in {0,32,64,96}

  float acc[32];
#pragma unroll
  for (int i = 0; i < 32; ++i) acc[i] = 0.f;

  int cph = 0;                              // (chunk*32) mod 160
  for (int chunk = 0; chunk < NCHUNK; ++chunk) {
    const int t0 = chunk * TC;
    __syncthreads();                        // prev chunk's LDS reads done
    {
      // stage q: 32 rows
#pragma unroll
      for (int it = 0; it < 2; ++it) {
        int row = rbase + it * 16;
        int traw = (t0 + row) * S;
        float4 v = pool_load<S>(Q + gbase + (size_t)traw * C_ + l16 * 4);
        *(float4*)(qs + row * 64 + l16 * 4) = v;
      }
      if (chunk == 0) {
#pragma unroll
        for (int it = 0; it < 10; ++it) {
          int l = rbase + it * 16;
          int tk = (l - tau0 - 127 + 2048) & LMASK;
          float4 v = pool_load<S>(K + gbase + (size_t)tk * S * C_ + l16 * 4);
          *(float4*)(ks + l * 64 + l16 * 4) = v;
        }
      } else {
        int sp = cph + 128; if (sp >= CAPR) sp -= CAPR;
#pragma unroll
        for (int it = 0; it < 2; ++it) {
          int row = rbase + it * 16;
          int l = t0 + 128 + row;
          int tk = (l - tau0 - 127 + 2048) & LMASK;
          int p = sp + row; if (p >= CAPR) p -= CAPR;
          float4 v = pool_load<S>(K + gbase + (size_t)tk * S * C_ + l16 * 4);
          *(float4*)(ks + p * 64 + l16 * 4) = v;
        }
      }
      __syncthreads();
    }
    // ---- compute: two 16x32 register tiles over a 63-reg k-window
    int bp = bp0 + cph; if (bp >= CAPR) bp -= CAPR;   // wave-uniform
    float km[63];
    if (bp <= CAPR - 47) {
#pragma unroll
      for (int m = 0; m < 47; ++m) km[m] = ks[(bp + m) * 64 + e];
    } else {
#pragma unroll
      for (int m = 0; m < 47; ++m) {
        int p = bp + m; if (p >= CAPR) p -= CAPR;
        km[m] = ks[p * 64 + e];
      }
    }
#pragma unroll
    for (int jt = 0; jt < 16; ++jt) {
      float qv = qs[jt * 64 + e];
#pragma unroll
      for (int i = 0; i < 32; ++i) acc[i] = fmaf(qv, km[31 + jt - i], acc[i]);
    }
    if (bp <= CAPR - 63) {
#pragma unroll
      for (int m = 47; m < 63; ++m) km[m] = ks[(bp + m) * 64 + e];
    } else {
#pragma unroll
      for (int m = 47; m < 63; ++m) {
        int p = bp + m; if (p >= CAPR) p -= CAPR;
        km[m] = ks[p * 64 + e];
      }
    }
#pragma unroll
    for (int jt = 16; jt < 32; ++jt) {
      float qv = qs[jt * 64 + e];
#pragma unroll
      for (int i = 0; i < 32; ++i) acc[i] = fmaf(qv, km[31 + jt - i], acc[i]);
    }
    cph += 32; if (cph >= CAPR) cph -= CAPR;
  }
  // transpose in LDS, coalesced write (tau-contiguous rows) ----------------
  __syncthreads();
  float* wt = ks;  // 128*65 = 8320 floats <= 10240
#pragma unroll
  for (int i = 0; i < 32; ++i) wt[(slot32 + i) * 65 + e] = acc[i];
  __syncthreads();
  const int to = tid & 127;
  const size_t cbase = ((size_t)b * C_ + (size_t)h * 64) * LS + tau0 + to;
  for (int cr = tid >> 7; cr < 64; cr += 2)
    corr[cbase + (size_t)cr * LS] = wt[to * 65 + cr];
}

// ---------------------------------------------------------------------------
// K2 (merged scales): per-(scale,b) stats, cm partials, peak detect +
// compaction (one global atomic per block) + level-0 histogram.
// Grid: (C_/GCH, B, 3).
// ---------------------------------------------------------------------------
__launch_bounds__(256, 4)
__global__ void k_stats(const float* __restrict__ corrbase, float* __restrict__ cm,
                        double* s1, double* s2, u32* peak_cnt, u32* histA,
                        u32* pkbase) {
  __shared__ __align__(16) float rows[GCH * 1024];
  __shared__ u32 hist_s[256];
  __shared__ double red_d[8];
  __shared__ u32 wv[4], wbase[4];
  const int tid = threadIdx.x;
  const int sidx = blockIdx.z;
  const int b = blockIdx.y;
  const int sb = sidx * 16 + b;
  const int Ls = 1024 >> sidx;
  const int c0 = blockIdx.x * GCH;
  const int lane = tid & 63;
  const int wave = tid >> 6;
  hist_s[tid] = 0;
  {
    const float4* src4 =
        (const float4*)(corrbase + co(sidx) + ((size_t)b * C_ + c0) * Ls);
    float4* dst4 = (float4*)rows;
    const int n4 = GCH * Ls / 4;
    for (int i = tid; i < n4; i += 256) dst4[i] = src4[i];
  }
  __syncthreads();
  const int nt = Ls >> 8;         // taus per thread: 4/2/1
  float cmacc[4] = {0.f, 0.f, 0.f, 0.f};
  double ls1 = 0.0, ls2 = 0.0;
  u32 mycnt = 0;
  // ---- phase 1: stats + peak count + level-0 hist
  for (int g = 0; g < GCH; ++g) {
    const float* row = rows + g * Ls;
    for (int i = 0; i < nt; ++i) {
      int t = tid + (i << 8);
      float v = row[t];
      cmacc[i] += v;
      ls1 += (double)v;
      ls2 += (double)v * (double)v;
      bool pk = (t >= 1) && (t <= Ls - 2) && (v > row[t - 1]) && (v > row[t + 1]);
      if (pk) {
        ++mycnt;
        atomicAdd(&hist_s[f2key(v) >> 24], 1u);
      }
    }
  }
  // block-scan peak counts -> single global atomic for base
  u32 wc = mycnt;
  for (int off = 32; off; off >>= 1) wc += __shfl_down(wc, off, 64);
  if (lane == 0) wv[wave] = wc;
  __syncthreads();
  if (tid == 0) {
    u32 t = 0;
    for (int w = 0; w < 4; ++w) { wbase[w] = t; t += wv[w]; }
    u32 base = atomicAdd(&peak_cnt[sb * 16], t);
    for (int w = 0; w < 4; ++w) wbase[w] += base;
  }
  __syncthreads();
  // ---- phase 2: re-detect, compacted write at deterministic offsets
  const u32 cap = pk_cap(sidx);
  u32* dst_pk = pkbase + pk_off(sidx) + (u32)b * cap;
  u32 off_w = wbase[wave];
  const u64 below = (1ull << lane) - 1ull;
  for (int g = 0; g < GCH; ++g) {
    const float* row = rows + g * Ls;
    for (int i = 0; i < nt; ++i) {
      int t = tid + (i << 8);
      float v = row[t];
      bool pk = (t >= 1) && (t <= Ls - 2) && (v > row[t - 1]) && (v > row[t + 1]);
      u64 mask = __ballot(pk);
      if (pk) {
        u32 idx = off_w + (u32)__popcll(mask & below);
        if (idx < cap) dst_pk[idx] = f2key(v);
      }
      off_w += (u32)__popcll(mask);
    }
  }
  // cm partials: one unsafe float atomic per owned tau
  for (int i = 0; i < nt; ++i) {
    int t = tid + (i << 8);
    unsafeAtomicAdd(&cm[sb * 1024 + t], cmacc[i]);
  }
  // s1/s2: wave reduce -> block reduce -> one double atomic per block
  for (int off = 32; off; off >>= 1) {
    ls1 += __shfl_down(ls1, off, 64);
    ls2 += __shfl_down(ls2, off, 64);
  }
  if (lane == 0) { red_d[wave] = ls1; red_d[4 + wave] = ls2; }
  __syncthreads();
  if (tid == 0) {
    unsafeAtomicAdd(&s1[sb], red_d[0] + red_d[1] + red_d[2] + red_d[3]);
    unsafeAtomicAdd(&s2[sb], red_d[4] + red_d[5] + red_d[6] + red_d[7]);
  }
  if (hist_s[tid]) atomicAdd(&histA[sb * 256 + tid], hist_s[tid]);
}

// ---------------------------------------------------------------------------
// K3 (merged): one block per (scale,b). cm pk-count, MLP -> kvals, level-0
// radix scan (snapshot-then-write). Energy computed redundantly per block.
// ---------------------------------------------------------------------------
__global__ void k_mlp(const float* __restrict__ cm, const double* s1,
                      const double* s2, const u32* peak_cnt, const u32* histA,
                      int* rank_s, u32* prefix_s, u32* active, float* thresh,
                      const float* w1, const float* b1, const float* w2,
                      const float* b2, const float* w3, const float* b3) {
  __shared__ float wls[673];       // w1(96) b1(32) w2(512) b2(16) w3(16) b3(1)
  __shared__ float cmrow[1024];
  __shared__ int red_i[4];
  __shared__ u32 cum[256];
  const int tid = threadIdx.x;
  const int sb = blockIdx.x;
  const int sidx = sb >> 4;
  const int Ls = 1024 >> sidx;
  for (int i = tid; i < 96; i += 256) wls[i] = w1[i];
  for (int i = tid; i < 32; i += 256) wls[96 + i] = b1[i];
  for (int i = tid; i < 512; i += 256) wls[128 + i] = w2[i];
  if (tid < 16) wls[640 + tid] = b2[tid];
  if (tid < 16) wls[656 + tid] = w3[tid];
  if (tid == 0) wls[672] = b3[0];
  for (int i = tid; i < Ls; i += 256) cmrow[i] = cm[sb * 1024 + i];
  __syncthreads();
  int cnt = 0;
  for (int t = 1 + tid; t <= Ls - 2; t += 256) {
    float v = cmrow[t];
    cnt += (v > cmrow[t - 1]) && (v > cmrow[t + 1]);
  }
  for (int off = 32; off; off >>= 1) cnt += __shfl_down(cnt, off, 64);
  if ((tid & 63) == 0) red_i[tid >> 6] = cnt;
  __syncthreads();
  if (tid == 0) {
    double tot = 0.0;
    for (int j = 0; j < 16; ++j) tot += s2[sidx * 16 + j];
    float f0 = (float)(tot / (16.0 * (double)Ls));
    double N = (double)C_ * (double)Ls;
    float f1 = (float)((s2[sb] - s1[sb] * s1[sb] / N) / (N - 1.0));
    float f2 = (float)(red_i[0] + red_i[1] + red_i[2] + red_i[3]);
    float h1[32];
    for (int j = 0; j < 32; ++j)
      h1[j] = fmaxf(0.f, wls[j * 3] * f0 + wls[j * 3 + 1] * f1 + wls[j * 3 + 2] * f2 + wls[96 + j]);
    float h2[16];
    for (int j = 0; j < 16; ++j) {
      float a = wls[640 + j];
      for (int i = 0; i < 32; ++i) a += wls[128 + j * 32 + i] * h1[i];
      h2[j] = fmaxf(0.f, a);
    }
    float z = wls[672];
    for (int i = 0; i < 16; ++i) z += wls[656 + i] * h2[i];
    float ratio = 1.0f / (1.0f + __expf(-z));
    int kv = (int)(ratio * (float)Ls);
    kv = min(max(kv, 1), Ls);
    int cntb = (int)peak_cnt[sb * 16];
    active[sb] = (u32)(cntb > kv);
    thresh[sb] = -INFINITY;
    rank_s[sb] = kv;
    prefix_s[sb] = 0;
  }
  __syncthreads();
  // level-0 radix scan: parallel suffix-scan over 256 bins
  cum[tid] = histA[sb * 256 + tid];
  __syncthreads();
  for (int off = 1; off < 256; off <<= 1) {
    u32 add = (tid + off < 256) ? cum[tid + off] : 0u;
    __syncthreads();
    cum[tid] += add;
    __syncthreads();
  }
  u32 act_b = active[sb];
  u32 r = act_b ? (u32)rank_s[sb] : 0u;
  u32 cc = cum[tid];
  u32 cnext = (tid == 255) ? 0u : cum[tid + 1];
  __syncthreads();          // all snapshots done before any write
  if (act_b && r > 0 && cc >= r && cnext < r) {
    prefix_s[sb] = (u32)tid << 24;
    rank_s[sb] = (int)(r - cnext);
  }
}

// ---------------------------------------------------------------------------
// K_sel (levels 1..3): full key scan, LDS->global hist, ticket finisher does
// the parallel suffix-scan + snapshot-write refine. Grid: 3*16*NB_SEL.
// ---------------------------------------------------------------------------
__global__ void k_sel(const u32* __restrict__ pkbase, const u32* peak_cnt,
                      const u32* active, int* rank_s, u32* prefix_s,
                      u32* hist, u32* done, float* thresh, int level) {
  __shared__ u32 hist_s[256];
  __shared__ u32 cum[256];
  __shared__ u32 islast;
  const int tid = threadIdx.x;
  const int sb = blockIdx.x / NB_SEL;
  const int blk = blockIdx.x % NB_SEL;
  const int sidx = sb >> 4;
  hist_s[tid] = 0;
  if (tid == 0) islast = 0;
  __syncthreads();
  const int act = (int)active[sb];
  const u32 cap = pk_cap(sidx);
  u32 cnt = peak_cnt[sb * 16];
  if (cnt > cap) cnt = cap;
  if (act) {
    const u32 pref = prefix_s[sb];
    const int hi_sh = 32 - 8 * level;
    const int b_sh = 24 - 8 * level;
    const u32 lo = (u32)(((u64)cnt * (u64)blk) / NB_SEL);
    const u32 hi = (u32)(((u64)cnt * (u64)(blk + 1)) / NB_SEL);
    const u32* src = pkbase + pk_off(sidx) + (u32)(sb & 15) * cap;
    for (u32 i = lo + tid; i < hi; i += 256) {
      u32 key = src[i];
      if ((key >> hi_sh) == (pref >> hi_sh))
        atomicAdd(&hist_s[(key >> b_sh) & 255u], 1u);
    }
  }
  __syncthreads();
  if (hist_s[tid]) atomicAdd(&hist[sb * 256 + tid], hist_s[tid]);
  __syncthreads();                        // barrier drains all vmem (vmcnt(0))
  if (tid == 0) {
    __threadfence();
    u32 t = atomicAdd(&done[(level - 1) * 48 + sb], 1u);
    if (t == NB_SEL - 1) islast = 1;
  }
  __syncthreads();
  if (!islast) return;
  // ---- finisher (exactly one block per (scale,b))
  __threadfence();
  u32 hv = atomicAdd(&hist[sb * 256 + tid], 0u);    // atomic read
  cum[tid] = hv;
  hist[sb * 256 + tid] = 0;               // ready for next level
  __syncthreads();
  for (int off = 1; off < 256; off <<= 1) {
    u32 add = (tid + off < 256) ? cum[tid + off] : 0u;
    __syncthreads();
    cum[tid] += add;
    __syncthreads();
  }
  u32 r = act ? (u32)rank_s[sb] : 0u;
  u32 pref2 = act ? prefix_s[sb] : 0u;
  u32 cc = cum[tid];
  u32 cnext = (tid == 255) ? 0u : cum[tid + 1];
  __syncthreads();                        // snapshots before write
  if (act && r > 0 && cc >= r && cnext < r) {
    u32 np = pref2 | ((u32)tid << (24 - 8 * level));
    prefix_s[sb] = np;
    rank_s[sb] = (int)(r - cnext);
    if (level == 3) thresh[sb] = key2f(np);
  }
}

// ---------------------------------------------------------------------------
// K5a (merged): per-(scale,b,c) softmax stats. Grid: (8192, 3).
// ---------------------------------------------------------------------------
__global__ void k_softstats(const float* __restrict__ corrbase, const float* thresh,
                            float2* __restrict__ mZ) {
  __shared__ float row[1024];
  __shared__ float red_s[8];
  const int tid = threadIdx.x;
  const int bc = blockIdx.x;
  const int sidx = blockIdx.y;
  const int Ls = 1024 >> sidx;
  const float th = thresh[sidx * 16 + (bc >> 9)];
  const float* src = corrbase + co(sidx) + (size_t)bc * Ls;
  for (int t = tid; t < Ls; t += 256) row[t] = src[t];
  __syncthreads();
  float mx = 0.f;   // zeros always present in attn row -> true max >= 0
  for (int t = tid; t < Ls; t += 256) {
    float v = row[t];
    bool pk = (t >= 1) && (t <= Ls - 2) && (v > row[t - 1]) && (v > row[t + 1]) && (v >= th);
    if (pk) mx = fmaxf(mx, v);
  }
  for (int off = 32; off; off >>= 1) mx = fmaxf(mx, __shfl_down(mx, off, 64));
  if ((tid & 63) == 0) red_s[tid >> 6] = mx;
  __syncthreads();
  float m = fmaxf(fmaxf(red_s[0], red_s[1]), fmaxf(red_s[2], red_s[3]));
  float zs = 0.f;
  for (int t = tid; t < Ls; t += 256) {
    float v = row[t];
    bool pk = (t >= 1) && (t <= Ls - 2) && (v > row[t - 1]) && (v > row[t + 1]) && (v >= th);
    float a = pk ? v : 0.f;
    zs += __expf(a - m);
  }
  for (int off = 32; off; off >>= 1) zs += __shfl_down(zs, off, 64);
  if ((tid & 63) == 0) red_s[4 + (tid >> 6)] = zs;
  __syncthreads();
  if (tid == 0) {
    float Z = red_s[4] + red_s[5] + red_s[6] + red_s[7];
    mZ[sidx * 8192 + bc] = make_float2(m, 1.0f / Z);
  }
}

// ---------------------------------------------------------------------------
// K5b (s=2,4): o_s[b][tau][c] = softmax-weight * pooled v. 128-tau tiles.
// corr/mZ/thresh passed pre-offset for the scale.
// ---------------------------------------------------------------------------
__launch_bounds__(256, 4)
__global__ void k_apply(const float* __restrict__ corr, const float* __restrict__ V,
                        const float2* __restrict__ mZ, const float* thresh,
                        float* __restrict__ o, int Ls, int s) {
  __shared__ float ct[64][131];      // col j holds t = t0-1+j (clamped)
  __shared__ float m_s[64], rz_s[64];
  const int tid = threadIdx.x;
  const int b = blockIdx.z;
  const int c0 = blockIdx.y << 6;
  const int t0 = blockIdx.x << 7;
  {
    const int row0 = tid >> 7, jc = tid & 127;
    for (int rr = row0; rr < 64; rr += 2) {
      const float* src = corr + ((size_t)b * C_ + c0 + rr) * Ls;
      for (int j = jc; j < 130; j += 128) {
        int t = t0 - 1 + j;
        t = max(0, min(t, Ls - 1));
        ct[rr][j] = src[t];
      }
    }
  }
  if (tid < 64) {
    float2 v = mZ[b * C_ + c0 + tid];
    m_s[tid] = v.x; rz_s[tid] = v.y;
  }
  __syncthreads();
  const float th = thresh[b];
  const int cl = tid & 63, ts = tid >> 6;
  for (int ii = 0; ii < 32; ++ii) {
    int tl = ts + (ii << 2);
    int tg = t0 + tl;
    float vm = ct[cl][tl], vc = ct[cl][tl + 1], vp = ct[cl][tl + 2];
    bool pk = (tg >= 1) && (tg <= Ls - 2) && (vc > vm) && (vc > vp) && (vc >= th);
    float a = pk ? vc : 0.f;
    float w = __expf(a - m_s[cl]) * rz_s[cl];
    size_t vb = ((size_t)b * L_ + (size_t)tg * s) * C_ + c0 + cl;
    float vv;
    if (s == 2) vv = (V[vb] + V[vb + C_]) * 0.5f;
    else vv = ((V[vb] + V[vb + C_]) + (V[vb + 2 * C_] + V[vb + 3 * C_])) * 0.25f;
    o[((size_t)b * Ls + tg) * C_ + c0 + cl] = w * vv;
  }
}

// ---------------------------------------------------------------------------
// K5b-final (s=1): out = sw0*w*v + sw1*lerp(o2) + sw2*lerp(o4). 128-tau tiles.
// ---------------------------------------------------------------------------
__launch_bounds__(256, 4)
__global__ void k_apply_final(const float* __restrict__ corr, const float* __restrict__ V,
                              const float2* __restrict__ mZ, const float* thresh,
                              const float* __restrict__ o2, const float* __restrict__ o4,
                              const float* __restrict__ sw, float* __restrict__ out) {
  __shared__ float ct[64][131];
  __shared__ float m_s[64], rz_s[64];
  const int Ls = 1024;
  const int tid = threadIdx.x;
  const int b = blockIdx.z;
  const int c0 = blockIdx.y << 6;
  const int t0 = blockIdx.x << 7;
  {
    const int row0 = tid >> 7, jc = tid & 127;
    for (int rr = row0; rr < 64; rr += 2) {
      const float* src = corr + ((size_t)b * C_ + c0 + rr) * Ls;
      for (int j = jc; j < 130; j += 128) {
        int t = t0 - 1 + j;
        t = max(0, min(t, Ls - 1));
        ct[rr][j] = src[t];
      }
    }
  }
  if (tid < 64) {
    float2 v = mZ[b * C_ + c0 + tid];
    m_s[tid] = v.x; rz_s[tid] = v.y;
  }
  __syncthreads();
  const float th = thresh[b];
  const float sw0 = sw[0], sw1 = sw[1], sw2 = sw[2];
  const int cl = tid & 63, ts = tid >> 6;
  for (int ii = 0; ii < 32; ++ii) {
    int tl = ts + (ii << 2);
    int tg = t0 + tl;
    float vm = ct[cl][tl], vc = ct[cl][tl + 1], vp = ct[cl][tl + 2];
    bool pk = (tg >= 1) && (tg <= Ls - 2) && (vc > vm) && (vc > vp) && (vc >= th);
    float a = pk ? vc : 0.f;
    float w = __expf(a - m_s[cl]) * rz_s[cl];
    float v1 = V[((size_t)b * L_ + tg) * C_ + c0 + cl];
    float r = sw0 * w * v1;
    {
      float srcp = fmaxf((tg + 0.5f) * 0.5f - 0.5f, 0.f);
      int x0 = (int)srcp;
      float lam = srcp - (float)x0;
      int x1 = min(x0 + 1, 511);
      const float* p = o2 + (size_t)b * 512 * C_ + c0 + cl;
      r += sw1 * ((1.f - lam) * p[(size_t)x0 * C_] + lam * p[(size_t)x1 * C_]);
    }
    {
      float srcp = fmaxf((tg + 0.5f) * 0.25f - 0.5f, 0.f);
      int x0 = (int)srcp;
      float lam = srcp - (float)x0;
      int x1 = min(x0 + 1, 255);
      const float* p = o4 + (size_t)b * 256 * C_ + c0 + cl;
      r += sw2 * ((1.f - lam) * p[(size_t)x0 * C_] + lam * p[(size_t)x1 * C_]);
    }
    out[((size_t)b * L_ + tg) * C_ + c0 + cl] = r;
  }
}

// ---------------------------------------------------------------------------
extern "C" void kernel_launch(void* const* d_in, const int* in_sizes, int n_in,
                              void* d_out, int out_size, void* d_ws, size_t ws_size,
                              hipStream_t stream) {
  const float* Q  = (const float*)d_in[0];
  const float* Kk = (const float*)d_in[1];
  const float* V  = (const float*)d_in[2];
  const float* sw = (const float*)d_in[3];
  const float* w1 = (const float*)d_in[4];
  const float* b1 = (const float*)d_in[5];
  const float* w2 = (const float*)d_in[6];
  const float* b2 = (const float*)d_in[7];
  const float* w3 = (const float*)d_in[8];
  const float* b3 = (const float*)d_in[9];
  float* out = (float*)d_out;

  char* ws = (char*)d_ws;
  size_t p = 0;
  auto alloc = [&](size_t n) { char* r = ws + p; p = (p + n + 255) & ~(size_t)255; return r; };
  // corr for all 3 scales: [s1 | s2 | s4], elem offsets 0 / 8388608 / 12582912
  float*  corr = (float*)alloc((size_t)(8388608 + 4194304 + 2097152) * 4);  // 58.7 MB
  // o-region: o2 (16.8MB) + o4 (8.4MB); pk_buf (22.5MB) aliases it (pk dies
  // after k_sel level 3; o2/o4 born at k_apply, strictly later in-stream).
  char*   oreg = alloc((size_t)25165824);
  float*  o2   = (float*)oreg;
  float*  o4   = (float*)(oreg + 16777216);
  u32*    pk   = (u32*)oreg;
  float*  cm       = (float*)alloc(3 * 16 * 1024 * 4);
  float2* mZ       = (float2*)alloc(3 * 16 * 512 * 8);
  double* s1d      = (double*)alloc(48 * 8);
  double* s2d      = (double*)alloc(48 * 8);
  u32*    histA    = (u32*)alloc(3 * 16 * 256 * 4);
  u32*    histB    = (u32*)alloc(3 * 16 * 256 * 4);
  u32*    peak_cnt = (u32*)alloc(3 * 16 * 16 * 4);   // padded: 1 counter / 64B
  u32*    done     = (u32*)alloc(144 * 4);
  int*    rank_s   = (int*)alloc(48 * 4);
  u32*    prefix_s = (u32*)alloc(48 * 4);
  u32*    active   = (u32*)alloc(48 * 4);
  float*  thresh   = (float*)alloc(48 * 4);

  k_init<<<dim3(16), dim3(256), 0, stream>>>(histA, histB, peak_cnt, done,
                                             s1d, s2d, cm);
  k_corr1<<<dim3(128, 8), dim3(512), 0, stream>>>(Q, Kk, corr);
  k_corr<2><<<dim3(128, 4), dim3(256), 0, stream>>>(Q, Kk, corr + 8388608);
  k_corr<4><<<dim3(128, 2), dim3(256), 0, stream>>>(Q, Kk, corr + 12582912);
  k_stats<<<dim3(C_ / GCH, B_, 3), dim3(256), 0, stream>>>(
      corr, cm, s1d, s2d, peak_cnt, histA, pk);
  k_mlp<<<dim3(48), dim3(256), 0, stream>>>(
      cm, s1d, s2d, peak_cnt, histA, rank_s, prefix_s, active, thresh,
      w1, b1, w2, b2, w3, b3);
  for (int level = 1; level <= 3; ++level)
    k_sel<<<dim3(48 * NB_SEL), dim3(256), 0, stream>>>(
        pk, peak_cnt, active, rank_s, prefix_s, histB, done, thresh, level);
  k_softstats<<<dim3(8192, 3), dim3(256), 0, stream>>>(corr, thresh, mZ);
  k_apply<<<dim3(2, 8, 16), dim3(256), 0, stream>>>(
      corr + 12582912, V, mZ + 2 * 8192, thresh + 32, o4, 256, 4);
  k_apply<<<dim3(4, 8, 16), dim3(256), 0, stream>>>(
      corr + 8388608, V, mZ + 1 * 8192, thresh + 16, o2, 512, 2);
  k_apply_final<<<dim3(8, 8, 16), dim3(256), 0, stream>>>(
      corr, V, mZ, thresh, o2, o4, sw, out);
}